// Round 9
// baseline (149.255 us; speedup 1.0000x reference)
//
#include <hip/hip_runtime.h>
#include <hip/hip_bf16.h>

// SelfAttention N=8192, D_IN=512, D_K=64 (fp32 io).
// R8 = R7 resubmitted verbatim (R7 bench was lost to GPUAcquisitionTimeout).
// attn restructured around block-shared, double-buffered LDS K/V staging via
// global_load_lds (T3-lite):
//  - All 4 waves of a block read the SAME 64-key tile -> stage it once in LDS
//    (24KB: Khi 8K | Klo 8K | V 8K, layouts already lane-consecutive 16B).
//  - Double buffer + prefetch tile t+1 before computing tile t; __syncthreads
//    drains vmcnt and swaps. L2 latency hides under ~600cy of compute.
//  - P_lds shrunk to one region per wave (reused across u; per-wave in-order).
// qkv3/merge16 byte-identical to R6 for clean A/B on attn.

#define N_TOK 8192
#define D_INN 512
#define DK    64

typedef __attribute__((ext_vector_type(8))) short bf16x8;
typedef __attribute__((ext_vector_type(4))) float f32x4;

#define GLOAD_LDS16(gsrc, ldst) \
  __builtin_amdgcn_global_load_lds( \
      (const __attribute__((address_space(1))) unsigned int*)(gsrc), \
      (__attribute__((address_space(3))) unsigned int*)(ldst), 16, 0, 0)

static __device__ __forceinline__ unsigned f2bf_u(float f) {
  union { float f; unsigned u; } v; v.f = f;
  return (v.u + 0x7FFFu + ((v.u >> 16) & 1u)) >> 16;
}
static __device__ __forceinline__ unsigned short f2bf(float f) { return (unsigned short)f2bf_u(f); }
static __device__ __forceinline__ float bf2f(unsigned short h) {
  union { unsigned u; float f; } v; v.u = ((unsigned)h) << 16; return v.f;
}
static __device__ __forceinline__ unsigned truncpk(float a, float b) {
  union { float f; unsigned u; } x, y; x.f = a; y.f = b;
  return (x.u >> 16) | (y.u & 0xFFFF0000u);
}
static __device__ __forceinline__ void split2(float a, float b, unsigned& hi, unsigned& lo) {
  unsigned ha = f2bf_u(a), hb = f2bf_u(b);
  float ra = a - bf2f((unsigned short)ha);
  float rb = b - bf2f((unsigned short)hb);
  hi = ha | (hb << 16);
  lo = f2bf_u(ra) | (f2bf_u(rb) << 16);
}
static __device__ __forceinline__ void split8(const float* p, bf16x8& hi, bf16x8& lo) {
  float4 a = *(const float4*)p;
  float4 b = *(const float4*)(p + 4);
  union { unsigned u[4]; bf16x8 v; } H, L;
  split2(a.x, a.y, H.u[0], L.u[0]);
  split2(a.z, a.w, H.u[1], L.u[1]);
  split2(b.x, b.y, H.u[2], L.u[2]);
  split2(b.z, b.w, H.u[3], L.u[3]);
  hi = H.v; lo = L.v;
}
static __device__ __forceinline__ bf16x8 round8(const float* p) {
  float4 a = *(const float4*)p;
  float4 b = *(const float4*)(p + 4);
  union { unsigned u[4]; bf16x8 v; } H;
  H.u[0] = f2bf_u(a.x) | (f2bf_u(a.y) << 16);
  H.u[1] = f2bf_u(a.z) | (f2bf_u(a.w) << 16);
  H.u[2] = f2bf_u(b.x) | (f2bf_u(b.y) << 16);
  H.u[3] = f2bf_u(b.z) | (f2bf_u(b.w) << 16);
  return H.v;
}

// ---------------- QKV projection (inline X and W split) ----------------
__global__ __launch_bounds__(256, 2) void qkv3(
    const float* __restrict__ X,
    const float* __restrict__ Wq, const float* __restrict__ Wk, const float* __restrict__ Wv,
    unsigned short* __restrict__ qhp, unsigned short* __restrict__ qlp,
    unsigned short* __restrict__ kph, unsigned short* __restrict__ kpl,
    unsigned short* __restrict__ vp) {
  const int tid = threadIdx.x, w = tid >> 6, l = tid & 63;
  const int l15 = l & 15, g = l >> 4;
  const int t0 = blockIdx.x * 16;
  const int dq = w * 16;

  f32x4 aq = {0.f, 0.f, 0.f, 0.f}, ak = aq, av = aq;

  for (int kc = 0; kc < D_INN; kc += 32) {
    bf16x8 ah, al;
    split8(X + (t0 + l15) * D_INN + kc + g * 8, ah, al);

    const int woff = (dq + l15) * D_INN + kc + g * 8;
    bf16x8 bqh, bql, bkh, bkl;
    split8(Wq + woff, bqh, bql);
    split8(Wk + woff, bkh, bkl);
    bf16x8 bvh = round8(Wv + woff);

    aq = __builtin_amdgcn_mfma_f32_16x16x32_bf16(ah, bqh, aq, 0, 0, 0);
    aq = __builtin_amdgcn_mfma_f32_16x16x32_bf16(ah, bql, aq, 0, 0, 0);
    aq = __builtin_amdgcn_mfma_f32_16x16x32_bf16(al, bqh, aq, 0, 0, 0);
    ak = __builtin_amdgcn_mfma_f32_16x16x32_bf16(ah, bkh, ak, 0, 0, 0);
    ak = __builtin_amdgcn_mfma_f32_16x16x32_bf16(ah, bkl, ak, 0, 0, 0);
    ak = __builtin_amdgcn_mfma_f32_16x16x32_bf16(al, bkh, ak, 0, 0, 0);
    av = __builtin_amdgcn_mfma_f32_16x16x32_bf16(ah, bvh, av, 0, 0, 0);
    av = __builtin_amdgcn_mfma_f32_16x16x32_bf16(al, bvh, av, 0, 0, 0);
  }

#pragma unroll
  for (int r = 0; r < 4; r++) {
    float v = aq[r] * 0.125f;
    int row = t0 + g * 4 + r;
    unsigned short h = f2bf(v);
    qhp[row * DK + dq + l15] = h;
    qlp[row * DK + dq + l15] = f2bf(v - bf2f(h));
  }
#pragma unroll
  for (int r = 0; r < 4; r++) {
    float v = ak[r];
    int t = t0 + g * 4 + r;
    int d = dq + l15;
    int off = (t >> 5) * 2048 + ((t >> 4) & 1) * 1024 + (d >> 5) * 512 +
              ((t & 15) + (((d >> 3) & 3) << 4)) * 8 + (d & 7);
    unsigned short h = f2bf(v);
    kph[off] = h;
    kpl[off] = f2bf(v - bf2f(h));
  }
  {
    int tg = t0 + g * 4;
    int d = dq + l15;
    int off = (tg >> 5) * 2048 + (d >> 4) * 512 +
              (((d & 15) + (((tg >> 3) & 3) << 4))) * 8 + (tg & 7);
    uint2 pk;
    pk.x = f2bf_u(av[0]) | (f2bf_u(av[1]) << 16);
    pk.y = f2bf_u(av[2]) | (f2bf_u(av[3]) << 16);
    *(uint2*)(vp + off) = pk;
  }
}

// ---------------- stage one 64-key tile (24KB) into LDS ----------------
// chunk c (1KB): c<8 -> Khi, c<16 -> Klo, else V; wave w stages chunks [6w,6w+6).
static __device__ __forceinline__ void stage_tile(
    const unsigned short* __restrict__ kph, const unsigned short* __restrict__ kpl,
    const unsigned short* __restrict__ vp, int kti,
    unsigned short* lds, int w, int l) {
  const unsigned short* kb = kph + kti * 2048;
  const unsigned short* lb = kpl + kti * 2048;
  const unsigned short* vb = vp + kti * 2048;
#pragma unroll
  for (int j = 0; j < 6; ++j) {
    int chunk = w * 6 + j;
    const unsigned short* src = (chunk < 8) ? kb : ((chunk < 16) ? lb : vb);
    GLOAD_LDS16(src + (chunk & 7) * 512 + l * 8, lds + chunk * 512);
  }
}

// ---------------- flash attention ----------------
// grid 1024 = 64 qblocks x 16 key-splits; 256 thr (4 waves); wave: 32 q x 512 keys.
__global__ __launch_bounds__(256, 2) void attn5(
    const unsigned short* __restrict__ qhp, const unsigned short* __restrict__ qlp,
    const unsigned short* __restrict__ kph, const unsigned short* __restrict__ kpl,
    const unsigned short* __restrict__ vp,
    unsigned short* __restrict__ pnb, float* __restrict__ pden, float* __restrict__ pM) {
  __shared__ unsigned short kv_lds[2 * 12288];   // 2 x 24KB tile buffers
  __shared__ unsigned short P_lds[4 * 16 * 72];  // per-wave P transpose (reused per u)

  const int tid = threadIdx.x, w = tid >> 6, l = tid & 63;
  const int l15 = l & 15, g = l >> 4;
  const int qblk = blockIdx.x >> 4, ks = blockIdx.x & 15;
  const int wq0 = qblk * 128 + w * 32;

  // Q fragments (B-operand of swapped QK^T)
  bf16x8 qhf[2][2], qlf[2][2];
#pragma unroll
  for (int u = 0; u < 2; u++)
#pragma unroll
    for (int c = 0; c < 2; c++) {
      int row = wq0 + u * 16 + l15;
      qhf[u][c] = *(const bf16x8*)(qhp + row * DK + c * 32 + g * 8);
      qlf[u][c] = *(const bf16x8*)(qlp + row * DK + c * 32 + g * 8);
    }

  const short onec = (short)0x3F80;
  const bf16x8 ones = {onec, onec, onec, onec, onec, onec, onec, onec};

  f32x4 accO[2][4], accL[2];
  float m[2] = {-1e30f, -1e30f};
#pragma unroll
  for (int u = 0; u < 2; u++) {
    accL[u] = f32x4{0.f, 0.f, 0.f, 0.f};
#pragma unroll
    for (int ds = 0; ds < 4; ds++) accO[u][ds] = f32x4{0.f, 0.f, 0.f, 0.f};
  }

  const int kti0 = ks * 16;  // 32-key groups; tile t covers kti0 + 2t, +2t+1
  stage_tile(kph, kpl, vp, kti0, kv_lds, w, l);
  __syncthreads();

  for (int t = 0; t < 8; ++t) {
    const int cb = (t & 1) ? 12288 : 0;
    const int pb = 12288 - cb;
    // prefetch next tile into the other buffer (in flight across compute)
    const int ktin = (t < 7) ? (kti0 + 2 * t + 2) : (kti0 + 2 * t);
    stage_tile(kph, kpl, vp, ktin, kv_lds + pb, w, l);

    const unsigned short* Kh = kv_lds + cb;
    const unsigned short* Kl = Kh + 4096;
    const unsigned short* Vv = Kh + 8192;

    // S^T = K Q^T (scores: col = q = lane&15, row = key via (g, reg))
    f32x4 st[2][4];
#pragma unroll
    for (int s = 0; s < 4; s++) {
      bf16x8 khf[2], klf[2];
#pragma unroll
      for (int c = 0; c < 2; c++) {
        const int off = (s >> 1) * 2048 + (s & 1) * 1024 + c * 512 + l * 8;
        khf[c] = *(const bf16x8*)(Kh + off);
        klf[c] = *(const bf16x8*)(Kl + off);
      }
      __builtin_amdgcn_s_setprio(1);
#pragma unroll
      for (int u = 0; u < 2; u++) {
        f32x4 sa = {0.f, 0.f, 0.f, 0.f};
        sa = __builtin_amdgcn_mfma_f32_16x16x32_bf16(khf[0], qhf[u][0], sa, 0, 0, 0);
        sa = __builtin_amdgcn_mfma_f32_16x16x32_bf16(khf[1], qhf[u][1], sa, 0, 0, 0);
        sa = __builtin_amdgcn_mfma_f32_16x16x32_bf16(khf[0], qlf[u][0], sa, 0, 0, 0);
        sa = __builtin_amdgcn_mfma_f32_16x16x32_bf16(khf[1], qlf[u][1], sa, 0, 0, 0);
        sa = __builtin_amdgcn_mfma_f32_16x16x32_bf16(klf[0], qhf[u][0], sa, 0, 0, 0);
        sa = __builtin_amdgcn_mfma_f32_16x16x32_bf16(klf[1], qhf[u][1], sa, 0, 0, 0);
        st[u][s] = sa;
      }
      __builtin_amdgcn_s_setprio(0);
    }

    bf16x8 pa[2][2];
#pragma unroll
    for (int u = 0; u < 2; u++) {
      float t0m = fmaxf(fmaxf(st[u][0][0], st[u][0][1]), fmaxf(st[u][0][2], st[u][0][3]));
      float t1m = fmaxf(fmaxf(st[u][1][0], st[u][1][1]), fmaxf(st[u][1][2], st[u][1][3]));
      float t2m = fmaxf(fmaxf(st[u][2][0], st[u][2][1]), fmaxf(st[u][2][2], st[u][2][3]));
      float t3m = fmaxf(fmaxf(st[u][3][0], st[u][3][1]), fmaxf(st[u][3][2], st[u][3][3]));
      float tm = fmaxf(fmaxf(t0m, t1m), fmaxf(t2m, t3m));
      tm = fmaxf(tm, __shfl_xor(tm, 16, 64));
      tm = fmaxf(tm, __shfl_xor(tm, 32, 64));
      if (__any(tm > m[u] + 8.f)) {  // defer-max (THR=8)
        float mn = fmaxf(m[u], tm);
        float fac = __expf(m[u] - mn);
        m[u] = mn;
#pragma unroll
        for (int r = 0; r < 4; r++) {
          float fr = __shfl(fac, g * 4 + r, 64);
          accL[u][r] *= fr;
#pragma unroll
          for (int ds = 0; ds < 4; ds++) accO[u][ds][r] *= fr;
        }
      }
      // P -> per-wave LDS transpose (region reused across u; per-wave in-order)
      const int base = (w * 16 + l15) * 72;
#pragma unroll
      for (int s = 0; s < 4; s++) {
        float p0 = __expf(st[u][s][0] - m[u]);
        float p1 = __expf(st[u][s][1] - m[u]);
        float p2 = __expf(st[u][s][2] - m[u]);
        float p3 = __expf(st[u][s][3] - m[u]);
        *(unsigned*)&P_lds[base + s * 16 + g * 4]     = truncpk(p0, p1);
        *(unsigned*)&P_lds[base + s * 16 + g * 4 + 2] = truncpk(p2, p3);
      }
#pragma unroll
      for (int c = 0; c < 2; c++)
        pa[u][c] = *(const bf16x8*)&P_lds[base + c * 32 + g * 8];
      accL[u] = __builtin_amdgcn_mfma_f32_16x16x32_bf16(pa[u][0], ones, accL[u], 0, 0, 0);
      accL[u] = __builtin_amdgcn_mfma_f32_16x16x32_bf16(pa[u][1], ones, accL[u], 0, 0, 0);
    }

    // PV from staged V
    __builtin_amdgcn_s_setprio(1);
#pragma unroll
    for (int ds = 0; ds < 4; ds++) {
      bf16x8 vb[2];
#pragma unroll
      for (int c = 0; c < 2; c++)
        vb[c] = *(const bf16x8*)(Vv + c * 2048 + ds * 512 + l * 8);
#pragma unroll
      for (int u = 0; u < 2; u++) {
        accO[u][ds] = __builtin_amdgcn_mfma_f32_16x16x32_bf16(pa[u][0], vb[0], accO[u][ds], 0, 0, 0);
        accO[u][ds] = __builtin_amdgcn_mfma_f32_16x16x32_bf16(pa[u][1], vb[1], accO[u][ds], 0, 0, 0);
      }
    }
    __builtin_amdgcn_s_setprio(0);

    __syncthreads();  // drains vmcnt (prefetch) + lgkm; swap buffers
  }

  // write per-(qblock, key-split) partials (num bf16, den/M fp32)
#pragma unroll
  for (int u = 0; u < 2; u++) {
#pragma unroll
    for (int ds = 0; ds < 4; ds++)
#pragma unroll
      for (int r = 0; r < 4; r++)
        pnb[(size_t)ks * (N_TOK * DK) + (wq0 + u * 16 + g * 4 + r) * DK + ds * 16 + l15] =
            f2bf(accO[u][ds][r]);
    if (l15 == 0) {
#pragma unroll
      for (int r = 0; r < 4; r++) pden[ks * N_TOK + wq0 + u * 16 + g * 4 + r] = accL[u][r];
    }
    if (g == 0) pM[ks * N_TOK + wq0 + u * 16 + l15] = m[u];
  }
}

// ---------------- merge 16 key-split partials ----------------
__global__ __launch_bounds__(256) void merge16(
    const unsigned short* __restrict__ pnb, const float* __restrict__ pden,
    const float* __restrict__ pM, float* __restrict__ out) {
  int i = blockIdx.x * 256 + threadIdx.x;
  int q = i >> 6, d = i & 63;
  float M = -1e30f;
#pragma unroll
  for (int s = 0; s < 16; s++) M = fmaxf(M, pM[s * N_TOK + q]);
  float num = 0.f, den = 0.f;
#pragma unroll
  for (int s = 0; s < 16; s++) {
    float e = __expf(pM[s * N_TOK + q] - M);
    num += bf2f(pnb[(size_t)s * (N_TOK * DK) + q * DK + d]) * e;
    den += pden[s * N_TOK + q] * e;
  }
  out[i] = num / den;
}

// ---------------- host launch ----------------
extern "C" void kernel_launch(void* const* d_in, const int* in_sizes, int n_in,
                              void* d_out, int out_size, void* d_ws, size_t ws_size,
                              hipStream_t stream) {
  (void)in_sizes; (void)n_in; (void)out_size; (void)ws_size;
  const float* X  = (const float*)d_in[0];
  const float* Wq = (const float*)d_in[1];
  const float* Wk = (const float*)d_in[2];
  const float* Wv = (const float*)d_in[3];

  char* base = (char*)d_ws;
  unsigned short* pnb = (unsigned short*)(base);                  // 16 MB [16][8192][64] bf16
  unsigned short* qhp = (unsigned short*)(base + 16777216);       // 1 MB
  unsigned short* qlp = (unsigned short*)(base + 17825792);       // 1 MB
  unsigned short* kph = (unsigned short*)(base + 18874368);       // 1 MB
  unsigned short* kpl = (unsigned short*)(base + 19922944);       // 1 MB
  unsigned short* vp  = (unsigned short*)(base + 20971520);       // 1 MB
  float* pden = (float*)(base + 22020096);                        // 512 KB
  float* pM   = (float*)(base + 22544384);                        // 512 KB

  qkv3<<<N_TOK / 16, 256, 0, stream>>>(X, Wq, Wk, Wv, qhp, qlp, kph, kpl, vp);
  attn5<<<1024, 256, 0, stream>>>(qhp, qlp, kph, kpl, vp, pnb, pden, pM);
  merge16<<<(N_TOK * DK) / 256, 256, 0, stream>>>(pnb, pden, pM, (float*)d_out);
}